// Round 1
// baseline (451.970 us; speedup 1.0000x reference)
//
#include <hip/hip_runtime.h>
#include <hip/hip_bf16.h>

typedef unsigned short u16;
typedef unsigned int u32;
typedef __attribute__((ext_vector_type(8))) short bf16x8;
typedef __attribute__((ext_vector_type(4))) float f32x4;

#define LQ 9216
#define CC 768
#define NH 6
#define DH 128
#define HH 96
#define WW 96

__device__ __forceinline__ u16 f2bf(float f) {
  union { float f; u32 u; } x; x.f = f;
  u32 r = x.u + 0x7fff + ((x.u >> 16) & 1);
  return (u16)(r >> 16);
}
__device__ __forceinline__ float bf2f(u16 u) {
  union { u32 u; float f; } x; x.u = ((u32)u) << 16; return x.f;
}

__device__ __forceinline__ void gl_lds16(const void* g, void* l) {
  __builtin_amdgcn_global_load_lds((const __attribute__((address_space(1))) void*)g,
                                   (__attribute__((address_space(3))) void*)l, 16, 0, 0);
}

// ---------------------------------------------------------------------------
// Weight prep: fp32 -> bf16 for the four 768x768 mats; build zero-padded
// [128,768] concat(so_w, aw_w) mats + padded [128] biases.
// ---------------------------------------------------------------------------
__global__ __launch_bounds__(256)
void prep_weights(const float* __restrict__ vp, const float* __restrict__ op,
                  const float* __restrict__ vp2, const float* __restrict__ op2,
                  const float* __restrict__ so, const float* __restrict__ aw,
                  const float* __restrict__ so2, const float* __restrict__ aw2,
                  const float* __restrict__ so_b, const float* __restrict__ aw_b,
                  const float* __restrict__ so2_b, const float* __restrict__ aw2_b,
                  u16* __restrict__ w4, u16* __restrict__ cat1, u16* __restrict__ cat2,
                  float* __restrict__ b1, float* __restrict__ b2) {
  const int i = blockIdx.x * 256 + threadIdx.x;
  const int NW = 589824;
  if (i < 4 * NW) {
    const int m = i / NW, r = i - m * NW;
    const float* s = (m == 0) ? vp : (m == 1) ? op : (m == 2) ? vp2 : op2;
    w4[i] = f2bf(s[r]);
  } else if (i < 4 * NW + 2 * 98304) {
    const int j = i - 4 * NW;
    const int which = j / 98304;
    const int r = j - which * 98304;
    const int row = r / 768, colr = r - row * 768;
    float v = 0.f;
    if (row < 48) v = (which ? so2 : so)[row * 768 + colr];
    else if (row < 72) v = (which ? aw2 : aw)[(row - 48) * 768 + colr];
    (which ? cat2 : cat1)[r] = f2bf(v);
  } else if (i < 4 * NW + 2 * 98304 + 256) {
    const int j = i - 4 * NW - 2 * 98304;
    const int which = j >> 7, row = j & 127;
    float v = 0.f;
    if (row < 48) v = (which ? so2_b : so_b)[row];
    else if (row < 72) v = (which ? aw2_b : aw_b)[row - 48];
    (which ? b2 : b1)[row] = v;
  }
}

// ---------------------------------------------------------------------------
// LayerNorm over C=768, one block (256 thr) per row, bf16 output.
// ---------------------------------------------------------------------------
__global__ __launch_bounds__(256)
void ln_to_bf16(const float* __restrict__ x, const float* __restrict__ w,
                const float* __restrict__ b, u16* __restrict__ out) {
  const int row = blockIdx.x;
  const int t = threadIdx.x;
  const float* xr = x + (size_t)row * CC;
  float v0 = xr[t], v1 = xr[t + 256], v2 = xr[t + 512];
  float s = v0 + v1 + v2;
  float ss = v0 * v0 + v1 * v1 + v2 * v2;
  #pragma unroll
  for (int o = 32; o > 0; o >>= 1) {
    s += __shfl_xor(s, o, 64);
    ss += __shfl_xor(ss, o, 64);
  }
  __shared__ float rs[4], rss[4];
  const int wv = t >> 6, ln = t & 63;
  if (ln == 0) { rs[wv] = s; rss[wv] = ss; }
  __syncthreads();
  s = rs[0] + rs[1] + rs[2] + rs[3];
  ss = rss[0] + rss[1] + rss[2] + rss[3];
  const float mu = s * (1.f / 768.f);
  const float var = ss * (1.f / 768.f) - mu * mu;
  const float rstd = rsqrtf(var + 1e-6f);
  u16* orow = out + (size_t)row * CC;
  orow[t]       = f2bf((v0 - mu) * rstd * w[t]       + b[t]);
  orow[t + 256] = f2bf((v1 - mu) * rstd * w[t + 256] + b[t + 256]);
  orow[t + 512] = f2bf((v2 - mu) * rstd * w[t + 512] + b[t + 512]);
}

// ---------------------------------------------------------------------------
// bf16 MFMA GEMM (m97 pattern): out[m][n] = sum_k A[m][k]*W[n][k] + bias[n]
// A:[M,K] bf16, W:[N,K] bf16 (B^T layout). 128x128 tile, BK=32, 256 threads,
// 4 waves each 64x64 via 4x4 mfma_f32_16x16x32_bf16. global_load_lds width 16.
// MODE 0: bf16 out; MODE 1: f32 out; MODE 2: f32 out = res + gamma[n]*(acc+bias)
// ---------------------------------------------------------------------------
template <int MODE>
__global__ __launch_bounds__(256)
void gemm_bt(const u16* __restrict__ A, const u16* __restrict__ W,
             const float* __restrict__ bias, void* __restrict__ outv,
             const float* __restrict__ res, const float* __restrict__ gamma,
             int M, int N, int K) {
  __shared__ u16 As[128 * 32];
  __shared__ u16 Bs[128 * 32];
  const int tid = threadIdx.x;
  const int wv = tid >> 6, lane = tid & 63;
  const int quad = lane >> 4, l16 = lane & 15;
  const int wm = wv & 1, wn = wv >> 1;
  const int m0 = blockIdx.x * 128, n0 = blockIdx.y * 128;
  const int srow = (wv << 4) + (lane >> 2);  // staging row 0..63
  const int scol = (lane & 3) << 3;          // staging col elem 0/8/16/24

  f32x4 acc[4][4];
  #pragma unroll
  for (int i = 0; i < 4; ++i)
    #pragma unroll
    for (int j = 0; j < 4; ++j)
      acc[i][j] = (f32x4){0.f, 0.f, 0.f, 0.f};

  const u16* ag = A + (size_t)(m0 + srow) * K + scol;
  const u16* bg = W + (size_t)(n0 + srow) * K + scol;
  u16* la = As + wv * 512 + lane * 8;  // wave-contiguous: base + lane*16B
  u16* lb = Bs + wv * 512 + lane * 8;

  for (int k0 = 0; k0 < K; k0 += 32) {
    __syncthreads();
    gl_lds16(ag + k0, la);
    gl_lds16(ag + (size_t)64 * K + k0, la + 2048);
    gl_lds16(bg + k0, lb);
    gl_lds16(bg + (size_t)64 * K + k0, lb + 2048);
    __syncthreads();
    bf16x8 af[4], bfr[4];
    #pragma unroll
    for (int i = 0; i < 4; ++i)
      af[i] = *(const bf16x8*)(As + ((wm * 64 + i * 16 + l16) * 32 + quad * 8));
    #pragma unroll
    for (int j = 0; j < 4; ++j)
      bfr[j] = *(const bf16x8*)(Bs + ((wn * 64 + j * 16 + l16) * 32 + quad * 8));
    #pragma unroll
    for (int i = 0; i < 4; ++i)
      #pragma unroll
      for (int j = 0; j < 4; ++j)
        acc[i][j] = __builtin_amdgcn_mfma_f32_16x16x32_bf16(af[i], bfr[j], acc[i][j], 0, 0, 0);
  }

  #pragma unroll
  for (int i = 0; i < 4; ++i) {
    #pragma unroll
    for (int j = 0; j < 4; ++j) {
      const int col = n0 + wn * 64 + j * 16 + l16;
      const float bs = bias[col];
      #pragma unroll
      for (int r = 0; r < 4; ++r) {
        const int row = m0 + wm * 64 + i * 16 + quad * 4 + r;
        const float v = acc[i][j][r] + bs;
        const size_t o = (size_t)row * N + col;
        if (MODE == 0) ((u16*)outv)[o] = f2bf(v);
        else if (MODE == 1) ((float*)outv)[o] = v;
        else ((float*)outv)[o] = res[o] + gamma[col] * v;
      }
    }
  }
}

// ---------------------------------------------------------------------------
// Deformable sampling: one wave per (q, head). Softmax over 4 points,
// bilinear gather (zero-pad OOB) from value[9216, 768] bf16, lane = 2 channels.
// offaw: [LQ,128]: cols 0..47 = offsets (h*8+p*2+{x,y}), 48..71 = aw logits.
// ---------------------------------------------------------------------------
__global__ __launch_bounds__(256)
void msds_sample(const u16* __restrict__ value, const float* __restrict__ offaw,
                 const float* __restrict__ ref, u16* __restrict__ out) {
  const int gid = blockIdx.x * 4 + (threadIdx.x >> 6);
  const int lane = threadIdx.x & 63;
  const int q = gid / NH;
  const int h = gid - q * NH;
  const float* oa = offaw + (size_t)q * 128;
  const float rx = ref[q * 2] * (float)WW - 0.5f;
  const float ry = ref[q * 2 + 1] * (float)HH - 0.5f;

  const float lg0 = oa[48 + h * 4 + 0], lg1 = oa[48 + h * 4 + 1];
  const float lg2 = oa[48 + h * 4 + 2], lg3 = oa[48 + h * 4 + 3];
  const float mx = fmaxf(fmaxf(lg0, lg1), fmaxf(lg2, lg3));
  const float e0 = __expf(lg0 - mx), e1 = __expf(lg1 - mx);
  const float e2 = __expf(lg2 - mx), e3 = __expf(lg3 - mx);
  const float inv = 1.f / (e0 + e1 + e2 + e3);
  const float wp[4] = {e0 * inv, e1 * inv, e2 * inv, e3 * inv};

  float acc0 = 0.f, acc1 = 0.f;
  const u16* vbase = value + h * DH + lane * 2;
  #pragma unroll
  for (int p = 0; p < 4; ++p) {
    const float px = rx + oa[h * 8 + p * 2];
    const float py = ry + oa[h * 8 + p * 2 + 1];
    const float fxf = floorf(px), fyf = floorf(py);
    const int x0 = (int)fxf, y0 = (int)fyf;
    const float fx = px - fxf, fy = py - fyf;
    const float w00 = wp[p] * (1.f - fy) * (1.f - fx);
    const float w01 = wp[p] * (1.f - fy) * fx;
    const float w10 = wp[p] * fy * (1.f - fx);
    const float w11 = wp[p] * fy * fx;
    #pragma unroll
    for (int cy = 0; cy < 2; ++cy) {
      const int yy = y0 + cy;
      if (yy < 0 || yy >= HH) continue;
      #pragma unroll
      for (int cx = 0; cx < 2; ++cx) {
        const int xx = x0 + cx;
        if (xx < 0 || xx >= WW) continue;
        const float w2 = cy ? (cx ? w11 : w10) : (cx ? w01 : w00);
        const u32 u = *(const u32*)(vbase + (size_t)(yy * WW + xx) * CC);
        acc0 += w2 * bf2f((u16)(u & 0xffff));
        acc1 += w2 * bf2f((u16)(u >> 16));
      }
    }
  }
  const u32 o = (u32)f2bf(acc0) | ((u32)f2bf(acc1) << 16);
  *(u32*)(out + (size_t)q * CC + h * DH + lane * 2) = o;
}

// ---------------------------------------------------------------------------
extern "C" void kernel_launch(void* const* d_in, const int* in_sizes, int n_in,
                              void* d_out, int out_size, void* d_ws, size_t ws_size,
                              hipStream_t stream) {
  const float* query = (const float*)d_in[0];
  const float* refp  = (const float*)d_in[1];
  const float* feat  = (const float*)d_in[2];
  const float* feat2 = (const float*)d_in[3];
  const float* qn_w = (const float*)d_in[6];
  const float* qn_b = (const float*)d_in[7];
  const float* fn_w = (const float*)d_in[8];
  const float* fn_b = (const float*)d_in[9];
  const float* so_w = (const float*)d_in[10];
  const float* so_b = (const float*)d_in[11];
  const float* aw_w = (const float*)d_in[12];
  const float* aw_b = (const float*)d_in[13];
  const float* vp_w = (const float*)d_in[14];
  const float* vp_b = (const float*)d_in[15];
  const float* op_w = (const float*)d_in[16];
  const float* op_b = (const float*)d_in[17];
  const float* gamma = (const float*)d_in[18];
  const float* qn2_w = (const float*)d_in[19];
  const float* qn2_b = (const float*)d_in[20];
  const float* fn2_w = (const float*)d_in[21];
  const float* fn2_b = (const float*)d_in[22];
  const float* so2_w = (const float*)d_in[23];
  const float* so2_b = (const float*)d_in[24];
  const float* aw2_w = (const float*)d_in[25];
  const float* aw2_b = (const float*)d_in[26];
  const float* vp2_w = (const float*)d_in[27];
  const float* vp2_b = (const float*)d_in[28];
  const float* op2_w = (const float*)d_in[29];
  const float* op2_b = (const float*)d_in[30];
  const float* gamma2 = (const float*)d_in[31];

  char* ws = (char*)d_ws;
  size_t off = 0;
  auto alloc = [&](size_t bytes) -> void* {
    void* p = ws + off;
    off += (bytes + 255) & ~(size_t)255;
    return p;
  };
  u16* w4    = (u16*)alloc((size_t)4 * 589824 * 2);
  u16* cat1  = (u16*)alloc((size_t)98304 * 2);
  u16* cat2  = (u16*)alloc((size_t)98304 * 2);
  float* b1  = (float*)alloc(128 * 4);
  float* b2  = (float*)alloc(128 * 4);
  u16* qn    = (u16*)alloc((size_t)LQ * CC * 2);  // reused as qn2
  u16* fn    = (u16*)alloc((size_t)LQ * CC * 2);  // reused as a_pre
  u16* fn2   = (u16*)alloc((size_t)LQ * CC * 2);  // reused as a2_pre
  u16* val1  = (u16*)alloc((size_t)LQ * CC * 2);
  u16* val2  = (u16*)alloc((size_t)LQ * CC * 2);
  float* offaw = (float*)alloc((size_t)LQ * 128 * 4);  // both rounds
  float* qbuf  = (float*)alloc((size_t)LQ * CC * 4);

  dim3 blk(256);
  dim3 gbig(LQ / 128, CC / 128), gsm(LQ / 128, 1);

  prep_weights<<<9985, blk, 0, stream>>>(vp_w, op_w, vp2_w, op2_w, so_w, aw_w, so2_w, aw2_w,
                                         so_b, aw_b, so2_b, aw2_b, w4, cat1, cat2, b1, b2);
  ln_to_bf16<<<LQ, blk, 0, stream>>>(query, qn_w, qn_b, qn);
  ln_to_bf16<<<LQ, blk, 0, stream>>>(feat, fn_w, fn_b, fn);
  ln_to_bf16<<<LQ, blk, 0, stream>>>(feat2, fn2_w, fn2_b, fn2);
  // value projections (value2 is independent of block 1 -> do both now)
  gemm_bt<0><<<gbig, blk, 0, stream>>>(fn,  w4,              vp_b,  (void*)val1, nullptr, nullptr, LQ, CC, CC);
  gemm_bt<0><<<gbig, blk, 0, stream>>>(fn2, w4 + 2 * 589824, vp2_b, (void*)val2, nullptr, nullptr, LQ, CC, CC);
  // block 1: offsets+weights, sample, out-proj + residual
  gemm_bt<1><<<gsm, blk, 0, stream>>>(qn, cat1, b1, (void*)offaw, nullptr, nullptr, LQ, 128, CC);
  msds_sample<<<LQ * NH / 4, blk, 0, stream>>>(val1, offaw, refp, fn);  // a_pre -> fn
  gemm_bt<2><<<gbig, blk, 0, stream>>>(fn, w4 + 589824, op_b, (void*)qbuf, query, gamma, LQ, CC, CC);
  // block 2
  ln_to_bf16<<<LQ, blk, 0, stream>>>(qbuf, qn2_w, qn2_b, qn);  // qn2 -> qn
  gemm_bt<1><<<gsm, blk, 0, stream>>>(qn, cat2, b2, (void*)offaw, nullptr, nullptr, LQ, 128, CC);
  msds_sample<<<LQ * NH / 4, blk, 0, stream>>>(val2, offaw, refp, fn2);  // a2_pre -> fn2
  gemm_bt<2><<<gbig, blk, 0, stream>>>(fn2, w4 + 3 * 589824, op2_b, d_out, qbuf, gamma2, LQ, CC, CC);
}

// Round 2
// 361.258 us; speedup vs baseline: 1.2511x; 1.2511x over previous
//
#include <hip/hip_runtime.h>
#include <hip/hip_bf16.h>

typedef unsigned short u16;
typedef unsigned int u32;
typedef __attribute__((ext_vector_type(8))) short bf16x8;
typedef __attribute__((ext_vector_type(4))) float f32x4;
typedef __attribute__((ext_vector_type(4))) u32 u32x4;

#define LQ 9216
#define CC 768
#define NH 6
#define DH 128
#define HH 96
#define WW 96

__device__ __forceinline__ u16 f2bf(float f) {
  union { float f; u32 u; } x; x.f = f;
  u32 r = x.u + 0x7fff + ((x.u >> 16) & 1);
  return (u16)(r >> 16);
}
__device__ __forceinline__ float u2f(u32 u) {
  union { u32 u; float f; } x; x.u = u; return x.f;
}

__device__ __forceinline__ void gl_lds16(const void* g, void* l) {
  __builtin_amdgcn_global_load_lds((const __attribute__((address_space(1))) void*)g,
                                   (__attribute__((address_space(3))) void*)l, 16, 0, 0);
}

// ---------------------------------------------------------------------------
// Weight prep: fp32 -> bf16 for the four 768x768 mats; build zero-padded
// [128,768] concat(so_w, aw_w) mats + padded [128] biases.
// ---------------------------------------------------------------------------
__global__ __launch_bounds__(256)
void prep_weights(const float* __restrict__ vp, const float* __restrict__ op,
                  const float* __restrict__ vp2, const float* __restrict__ op2,
                  const float* __restrict__ so, const float* __restrict__ aw,
                  const float* __restrict__ so2, const float* __restrict__ aw2,
                  const float* __restrict__ so_b, const float* __restrict__ aw_b,
                  const float* __restrict__ so2_b, const float* __restrict__ aw2_b,
                  u16* __restrict__ w4, u16* __restrict__ cat1, u16* __restrict__ cat2,
                  float* __restrict__ b1, float* __restrict__ b2) {
  const int i = blockIdx.x * 256 + threadIdx.x;
  const int NW = 589824;
  if (i < 4 * NW) {
    const int m = i / NW, r = i - m * NW;
    const float* s = (m == 0) ? vp : (m == 1) ? op : (m == 2) ? vp2 : op2;
    w4[i] = f2bf(s[r]);
  } else if (i < 4 * NW + 2 * 98304) {
    const int j = i - 4 * NW;
    const int which = j / 98304;
    const int r = j - which * 98304;
    const int row = r / 768, colr = r - row * 768;
    float v = 0.f;
    if (row < 48) v = (which ? so2 : so)[row * 768 + colr];
    else if (row < 72) v = (which ? aw2 : aw)[(row - 48) * 768 + colr];
    (which ? cat2 : cat1)[r] = f2bf(v);
  } else if (i < 4 * NW + 2 * 98304 + 256) {
    const int j = i - 4 * NW - 2 * 98304;
    const int which = j >> 7, row = j & 127;
    float v = 0.f;
    if (row < 48) v = (which ? so2_b : so_b)[row];
    else if (row < 72) v = (which ? aw2_b : aw_b)[row - 48];
    (which ? b2 : b1)[row] = v;
  }
}

// ---------------------------------------------------------------------------
// LayerNorm over C=768, one block (256 thr) per row, bf16 output.
// ---------------------------------------------------------------------------
__device__ __forceinline__ void ln_body(const float* __restrict__ x, const float* __restrict__ w,
                                        const float* __restrict__ b, u16* __restrict__ out, int row) {
  const int t = threadIdx.x;
  const float* xr = x + (size_t)row * CC;
  float v0 = xr[t], v1 = xr[t + 256], v2 = xr[t + 512];
  float s = v0 + v1 + v2;
  float ss = v0 * v0 + v1 * v1 + v2 * v2;
  #pragma unroll
  for (int o = 32; o > 0; o >>= 1) {
    s += __shfl_xor(s, o, 64);
    ss += __shfl_xor(ss, o, 64);
  }
  __shared__ float rs[4], rss[4];
  const int wv = t >> 6, ln = t & 63;
  if (ln == 0) { rs[wv] = s; rss[wv] = ss; }
  __syncthreads();
  s = rs[0] + rs[1] + rs[2] + rs[3];
  ss = rss[0] + rss[1] + rss[2] + rss[3];
  const float mu = s * (1.f / 768.f);
  const float var = ss * (1.f / 768.f) - mu * mu;
  const float rstd = rsqrtf(var + 1e-6f);
  u16* orow = out + (size_t)row * CC;
  orow[t]       = f2bf((v0 - mu) * rstd * w[t]       + b[t]);
  orow[t + 256] = f2bf((v1 - mu) * rstd * w[t + 256] + b[t + 256]);
  orow[t + 512] = f2bf((v2 - mu) * rstd * w[t + 512] + b[t + 512]);
}

__global__ __launch_bounds__(256)
void ln_to_bf16(const float* __restrict__ x, const float* __restrict__ w,
                const float* __restrict__ b, u16* __restrict__ out) {
  ln_body(x, w, b, out, blockIdx.x);
}

// 3 independent LNs in one dispatch (blockIdx.y selects source).
__global__ __launch_bounds__(256)
void ln3_to_bf16(const float* __restrict__ x0, const float* __restrict__ w0, const float* __restrict__ b0, u16* __restrict__ o0,
                 const float* __restrict__ x1, const float* __restrict__ w1, const float* __restrict__ b1, u16* __restrict__ o1,
                 const float* __restrict__ x2, const float* __restrict__ w2, const float* __restrict__ b2, u16* __restrict__ o2) {
  const int sel = blockIdx.y;
  const float* x = (sel == 0) ? x0 : (sel == 1) ? x1 : x2;
  const float* w = (sel == 0) ? w0 : (sel == 1) ? w1 : w2;
  const float* b = (sel == 0) ? b0 : (sel == 1) ? b1 : b2;
  u16* o = (sel == 0) ? o0 : (sel == 1) ? o1 : o2;
  ln_body(x, w, b, o, blockIdx.x);
}

// ---------------------------------------------------------------------------
// bf16 MFMA GEMM core (m97 pattern): out[m][n] = sum_k A[m][k]*W[n][k] + bias[n]
// 128x128 tile, BK=32, 256 threads, 4 waves each 64x64 via 4x4 16x16x32 MFMA.
// MODE 0: bf16 out; MODE 1: f32 out; MODE 2: f32 out = res + gamma[n]*(acc+bias)
// ---------------------------------------------------------------------------
template <int MODE>
__device__ __forceinline__ void gemm_core(const u16* __restrict__ A, const u16* __restrict__ W,
                                          const float* __restrict__ bias, void* __restrict__ outv,
                                          const float* __restrict__ res, const float* __restrict__ gamma,
                                          int M, int N, int K, int m0, int n0) {
  __shared__ u16 As[128 * 32];
  __shared__ u16 Bs[128 * 32];
  const int tid = threadIdx.x;
  const int wv = tid >> 6, lane = tid & 63;
  const int quad = lane >> 4, l16 = lane & 15;
  const int wm = wv & 1, wn = wv >> 1;
  const int srow = (wv << 4) + (lane >> 2);
  const int scol = (lane & 3) << 3;

  f32x4 acc[4][4];
  #pragma unroll
  for (int i = 0; i < 4; ++i)
    #pragma unroll
    for (int j = 0; j < 4; ++j)
      acc[i][j] = (f32x4){0.f, 0.f, 0.f, 0.f};

  const u16* ag = A + (size_t)(m0 + srow) * K + scol;
  const u16* bg = W + (size_t)(n0 + srow) * K + scol;
  u16* la = As + wv * 512 + lane * 8;
  u16* lb = Bs + wv * 512 + lane * 8;

  for (int k0 = 0; k0 < K; k0 += 32) {
    __syncthreads();
    gl_lds16(ag + k0, la);
    gl_lds16(ag + (size_t)64 * K + k0, la + 2048);
    gl_lds16(bg + k0, lb);
    gl_lds16(bg + (size_t)64 * K + k0, lb + 2048);
    __syncthreads();
    bf16x8 af[4], bfr[4];
    #pragma unroll
    for (int i = 0; i < 4; ++i)
      af[i] = *(const bf16x8*)(As + ((wm * 64 + i * 16 + l16) * 32 + quad * 8));
    #pragma unroll
    for (int j = 0; j < 4; ++j)
      bfr[j] = *(const bf16x8*)(Bs + ((wn * 64 + j * 16 + l16) * 32 + quad * 8));
    #pragma unroll
    for (int i = 0; i < 4; ++i)
      #pragma unroll
      for (int j = 0; j < 4; ++j)
        acc[i][j] = __builtin_amdgcn_mfma_f32_16x16x32_bf16(af[i], bfr[j], acc[i][j], 0, 0, 0);
  }

  #pragma unroll
  for (int i = 0; i < 4; ++i) {
    #pragma unroll
    for (int j = 0; j < 4; ++j) {
      const int col = n0 + wn * 64 + j * 16 + l16;
      const float bs = bias[col];
      #pragma unroll
      for (int r = 0; r < 4; ++r) {
        const int row = m0 + wm * 64 + i * 16 + quad * 4 + r;
        const float v = acc[i][j][r] + bs;
        const size_t o = (size_t)row * N + col;
        if (MODE == 0) ((u16*)outv)[o] = f2bf(v);
        else if (MODE == 1) ((float*)outv)[o] = v;
        else ((float*)outv)[o] = res[o] + gamma[col] * v;
      }
    }
  }
}

template <int MODE>
__global__ __launch_bounds__(256)
void gemm_bt(const u16* __restrict__ A, const u16* __restrict__ W,
             const float* __restrict__ bias, void* __restrict__ outv,
             const float* __restrict__ res, const float* __restrict__ gamma,
             int M, int N, int K) {
  gemm_core<MODE>(A, W, bias, outv, res, gamma, M, N, K, blockIdx.x * 128, blockIdx.y * 128);
}

// Two independent value-projection GEMMs in one dispatch (blockIdx.z selects).
__global__ __launch_bounds__(256)
void gemm_val_dual(const u16* __restrict__ A0, const u16* __restrict__ W0, const float* __restrict__ b0, u16* __restrict__ o0,
                   const u16* __restrict__ A1, const u16* __restrict__ W1, const float* __restrict__ b1, u16* __restrict__ o1,
                   int M, int N, int K) {
  const int z = blockIdx.z;
  const u16* A = z ? A1 : A0;
  const u16* W = z ? W1 : W0;
  const float* b = z ? b1 : b0;
  u16* o = z ? o1 : o0;
  gemm_core<0>(A, W, b, (void*)o, nullptr, nullptr, M, N, K, blockIdx.x * 128, blockIdx.y * 128);
}

// ---------------------------------------------------------------------------
// Small GEMM [M,K]x[N,K]^T -> f32 [M,N], N=128: 64x64 tile, 288 blocks.
// ---------------------------------------------------------------------------
__global__ __launch_bounds__(256)
void gemm_small(const u16* __restrict__ A, const u16* __restrict__ W,
                const float* __restrict__ bias, float* __restrict__ out,
                int M, int N, int K) {
  __shared__ u16 As[64 * 32];
  __shared__ u16 Bs[64 * 32];
  const int tid = threadIdx.x;
  const int wv = tid >> 6, lane = tid & 63;
  const int quad = lane >> 4, l16 = lane & 15;
  const int wm = wv & 1, wn = wv >> 1;
  const int m0 = blockIdx.x * 64, n0 = blockIdx.y * 64;
  const int srow = tid >> 2;
  const int scol = (tid & 3) << 3;

  f32x4 acc[2][2];
  #pragma unroll
  for (int i = 0; i < 2; ++i)
    #pragma unroll
    for (int j = 0; j < 2; ++j)
      acc[i][j] = (f32x4){0.f, 0.f, 0.f, 0.f};

  const u16* ag = A + (size_t)(m0 + srow) * K + scol;
  const u16* bg = W + (size_t)(n0 + srow) * K + scol;
  u16* la = As + tid * 8;  // = wave base (wv*1024B) + lane*16B : wave-contiguous
  u16* lb = Bs + tid * 8;

  for (int k0 = 0; k0 < K; k0 += 32) {
    __syncthreads();
    gl_lds16(ag + k0, la);
    gl_lds16(bg + k0, lb);
    __syncthreads();
    bf16x8 af[2], bfr[2];
    #pragma unroll
    for (int i = 0; i < 2; ++i)
      af[i] = *(const bf16x8*)(As + ((wm * 32 + i * 16 + l16) * 32 + quad * 8));
    #pragma unroll
    for (int j = 0; j < 2; ++j)
      bfr[j] = *(const bf16x8*)(Bs + ((wn * 32 + j * 16 + l16) * 32 + quad * 8));
    #pragma unroll
    for (int i = 0; i < 2; ++i)
      #pragma unroll
      for (int j = 0; j < 2; ++j)
        acc[i][j] = __builtin_amdgcn_mfma_f32_16x16x32_bf16(af[i], bfr[j], acc[i][j], 0, 0, 0);
  }

  #pragma unroll
  for (int i = 0; i < 2; ++i) {
    #pragma unroll
    for (int j = 0; j < 2; ++j) {
      const int col = n0 + wn * 32 + j * 16 + l16;
      const float bs = bias[col];
      #pragma unroll
      for (int r = 0; r < 4; ++r) {
        const int row = m0 + wm * 32 + i * 16 + quad * 4 + r;
        out[(size_t)row * N + col] = acc[i][j][r] + bs;
      }
    }
  }
}

// ---------------------------------------------------------------------------
// Deformable sampling, vectorized: 16 lanes per (q,h), each lane 8 channels
// (dwordx4 loads). 4 (q,h) pairs per wave. Predicated OOB (clamp idx, zero w).
// offaw: [LQ,128]: cols 0..47 = offsets (h*8+p*2+{x,y}), 48..71 = aw logits.
// ---------------------------------------------------------------------------
__global__ __launch_bounds__(256)
void msds_sample(const u16* __restrict__ value, const float* __restrict__ offaw,
                 const float* __restrict__ ref, u16* __restrict__ out) {
  const int t = blockIdx.x * 256 + threadIdx.x;
  const int pi = t >> 4;   // (q,h) pair index
  const int gl = t & 15;   // lane within group: 8 channels each
  const int q = pi / NH;
  const int h = pi - q * NH;
  const float* oa = offaw + (size_t)q * 128;
  const float rx = ref[q * 2] * (float)WW - 0.5f;
  const float ry = ref[q * 2 + 1] * (float)HH - 0.5f;

  const float lg0 = oa[48 + h * 4 + 0], lg1 = oa[48 + h * 4 + 1];
  const float lg2 = oa[48 + h * 4 + 2], lg3 = oa[48 + h * 4 + 3];
  const float mx = fmaxf(fmaxf(lg0, lg1), fmaxf(lg2, lg3));
  const float e0 = __expf(lg0 - mx), e1 = __expf(lg1 - mx);
  const float e2 = __expf(lg2 - mx), e3 = __expf(lg3 - mx);
  const float inv = 1.f / (e0 + e1 + e2 + e3);
  const float wp[4] = {e0 * inv, e1 * inv, e2 * inv, e3 * inv};

  float acc[8];
  #pragma unroll
  for (int k = 0; k < 8; ++k) acc[k] = 0.f;

  const u16* vbase = value + h * DH + gl * 8;
  #pragma unroll
  for (int p = 0; p < 4; ++p) {
    const float px = rx + oa[h * 8 + p * 2];
    const float py = ry + oa[h * 8 + p * 2 + 1];
    const float fxf = floorf(px), fyf = floorf(py);
    const int x0 = (int)fxf, y0 = (int)fyf;
    const float fx = px - fxf, fy = py - fyf;
    const float cw[4] = {wp[p] * (1.f - fy) * (1.f - fx), wp[p] * (1.f - fy) * fx,
                         wp[p] * fy * (1.f - fx),         wp[p] * fy * fx};
    #pragma unroll
    for (int c = 0; c < 4; ++c) {
      const int yy = y0 + (c >> 1);
      const int xx = x0 + (c & 1);
      const bool valid = (yy >= 0) & (yy < HH) & (xx >= 0) & (xx < WW);
      const int yc = min(max(yy, 0), HH - 1);
      const int xc = min(max(xx, 0), WW - 1);
      const float w2 = valid ? cw[c] : 0.f;
      const u32x4 u = *(const u32x4*)(vbase + (size_t)(yc * WW + xc) * CC);
      #pragma unroll
      for (int k = 0; k < 4; ++k) {
        acc[2 * k]     += w2 * u2f(u[k] << 16);
        acc[2 * k + 1] += w2 * u2f(u[k] & 0xffff0000u);
      }
    }
  }
  u32x4 o;
  #pragma unroll
  for (int k = 0; k < 4; ++k)
    o[k] = (u32)f2bf(acc[2 * k]) | ((u32)f2bf(acc[2 * k + 1]) << 16);
  *(u32x4*)(out + (size_t)q * CC + h * DH + gl * 8) = o;
}

// ---------------------------------------------------------------------------
extern "C" void kernel_launch(void* const* d_in, const int* in_sizes, int n_in,
                              void* d_out, int out_size, void* d_ws, size_t ws_size,
                              hipStream_t stream) {
  const float* query = (const float*)d_in[0];
  const float* refp  = (const float*)d_in[1];
  const float* feat  = (const float*)d_in[2];
  const float* feat2 = (const float*)d_in[3];
  const float* qn_w = (const float*)d_in[6];
  const float* qn_b = (const float*)d_in[7];
  const float* fn_w = (const float*)d_in[8];
  const float* fn_b = (const float*)d_in[9];
  const float* so_w = (const float*)d_in[10];
  const float* so_b = (const float*)d_in[11];
  const float* aw_w = (const float*)d_in[12];
  const float* aw_b = (const float*)d_in[13];
  const float* vp_w = (const float*)d_in[14];
  const float* vp_b = (const float*)d_in[15];
  const float* op_w = (const float*)d_in[16];
  const float* op_b = (const float*)d_in[17];
  const float* gamma = (const float*)d_in[18];
  const float* qn2_w = (const float*)d_in[19];
  const float* qn2_b = (const float*)d_in[20];
  const float* fn2_w = (const float*)d_in[21];
  const float* fn2_b = (const float*)d_in[22];
  const float* so2_w = (const float*)d_in[23];
  const float* so2_b = (const float*)d_in[24];
  const float* aw2_w = (const float*)d_in[25];
  const float* aw2_b = (const float*)d_in[26];
  const float* vp2_w = (const float*)d_in[27];
  const float* vp2_b = (const float*)d_in[28];
  const float* op2_w = (const float*)d_in[29];
  const float* op2_b = (const float*)d_in[30];
  const float* gamma2 = (const float*)d_in[31];

  char* ws = (char*)d_ws;
  size_t off = 0;
  auto alloc = [&](size_t bytes) -> void* {
    void* p = ws + off;
    off += (bytes + 255) & ~(size_t)255;
    return p;
  };
  u16* w4    = (u16*)alloc((size_t)4 * 589824 * 2);
  u16* cat1  = (u16*)alloc((size_t)98304 * 2);
  u16* cat2  = (u16*)alloc((size_t)98304 * 2);
  float* b1  = (float*)alloc(128 * 4);
  float* b2  = (float*)alloc(128 * 4);
  u16* qn    = (u16*)alloc((size_t)LQ * CC * 2);  // reused as qn2
  u16* fn    = (u16*)alloc((size_t)LQ * CC * 2);  // reused as a_pre
  u16* fn2   = (u16*)alloc((size_t)LQ * CC * 2);  // reused as a2_pre
  u16* val1  = (u16*)alloc((size_t)LQ * CC * 2);
  u16* val2  = (u16*)alloc((size_t)LQ * CC * 2);
  float* offaw = (float*)alloc((size_t)LQ * 128 * 4);  // both rounds
  float* qbuf  = (float*)alloc((size_t)LQ * CC * 4);

  dim3 blk(256);
  dim3 gbig(LQ / 128, CC / 128), gdual(LQ / 128, CC / 128, 2), gsm(LQ / 64, 2);

  prep_weights<<<9985, blk, 0, stream>>>(vp_w, op_w, vp2_w, op2_w, so_w, aw_w, so2_w, aw2_w,
                                         so_b, aw_b, so2_b, aw2_b, w4, cat1, cat2, b1, b2);
  ln3_to_bf16<<<dim3(LQ, 3), blk, 0, stream>>>(query, qn_w, qn_b, qn,
                                               feat, fn_w, fn_b, fn,
                                               feat2, fn2_w, fn2_b, fn2);
  // both value projections in one dispatch (864 blocks)
  gemm_val_dual<<<gdual, blk, 0, stream>>>(fn, w4, vp_b, val1,
                                           fn2, w4 + 2 * 589824, vp2_b, val2, LQ, CC, CC);
  // block 1: offsets+weights, sample, out-proj + residual
  gemm_small<<<gsm, blk, 0, stream>>>(qn, cat1, b1, offaw, LQ, 128, CC);
  msds_sample<<<LQ * NH / 16, blk, 0, stream>>>(val1, offaw, refp, fn);  // a_pre -> fn
  gemm_bt<2><<<gbig, blk, 0, stream>>>(fn, w4 + 589824, op_b, (void*)qbuf, query, gamma, LQ, CC, CC);
  // block 2
  ln_to_bf16<<<LQ, blk, 0, stream>>>(qbuf, qn2_w, qn2_b, qn);  // qn2 -> qn
  gemm_small<<<gsm, blk, 0, stream>>>(qn, cat2, b2, offaw, LQ, 128, CC);
  msds_sample<<<LQ * NH / 16, blk, 0, stream>>>(val2, offaw, refp, fn2);  // a2_pre -> fn2
  gemm_bt<2><<<gbig, blk, 0, stream>>>(fn2, w4 + 3 * 589824, op2_b, d_out, qbuf, gamma2, LQ, CC, CC);
}

// Round 3
// 342.026 us; speedup vs baseline: 1.3214x; 1.0562x over previous
//
#include <hip/hip_runtime.h>
#include <hip/hip_bf16.h>

typedef unsigned short u16;
typedef unsigned int u32;
typedef __attribute__((ext_vector_type(8))) short bf16x8;
typedef __attribute__((ext_vector_type(4))) float f32x4;
typedef __attribute__((ext_vector_type(4))) u32 u32x4;

#define LQ 9216
#define CC 768
#define NH 6
#define DH 128
#define HH 96
#define WW 96

__device__ __forceinline__ u16 f2bf(float f) {
  union { float f; u32 u; } x; x.f = f;
  u32 r = x.u + 0x7fff + ((x.u >> 16) & 1);
  return (u16)(r >> 16);
}
__device__ __forceinline__ float u2f(u32 u) {
  union { u32 u; float f; } x; x.u = u; return x.f;
}

__device__ __forceinline__ void gl_lds16(const void* g, void* l) {
  __builtin_amdgcn_global_load_lds((const __attribute__((address_space(1))) void*)g,
                                   (__attribute__((address_space(3))) void*)l, 16, 0, 0);
}

// ---------------------------------------------------------------------------
// Weight prep: fp32 -> bf16 for the four 768x768 mats; build zero-padded
// [128,768] concat(so_w, aw_w) mats + padded [128] biases.
// ---------------------------------------------------------------------------
__global__ __launch_bounds__(256)
void prep_weights(const float* __restrict__ vp, const float* __restrict__ op,
                  const float* __restrict__ vp2, const float* __restrict__ op2,
                  const float* __restrict__ so, const float* __restrict__ aw,
                  const float* __restrict__ so2, const float* __restrict__ aw2,
                  const float* __restrict__ so_b, const float* __restrict__ aw_b,
                  const float* __restrict__ so2_b, const float* __restrict__ aw2_b,
                  u16* __restrict__ w4, u16* __restrict__ cat1, u16* __restrict__ cat2,
                  float* __restrict__ b1, float* __restrict__ b2) {
  const int i = blockIdx.x * 256 + threadIdx.x;
  const int NW = 589824;
  if (i < 4 * NW) {
    const int m = i / NW, r = i - m * NW;
    const float* s = (m == 0) ? vp : (m == 1) ? op : (m == 2) ? vp2 : op2;
    w4[i] = f2bf(s[r]);
  } else if (i < 4 * NW + 2 * 98304) {
    const int j = i - 4 * NW;
    const int which = j / 98304;
    const int r = j - which * 98304;
    const int row = r / 768, colr = r - row * 768;
    float v = 0.f;
    if (row < 48) v = (which ? so2 : so)[row * 768 + colr];
    else if (row < 72) v = (which ? aw2 : aw)[(row - 48) * 768 + colr];
    (which ? cat2 : cat1)[r] = f2bf(v);
  } else if (i < 4 * NW + 2 * 98304 + 256) {
    const int j = i - 4 * NW - 2 * 98304;
    const int which = j >> 7, row = j & 127;
    float v = 0.f;
    if (row < 48) v = (which ? so2_b : so_b)[row];
    else if (row < 72) v = (which ? aw2_b : aw_b)[row - 48];
    (which ? b2 : b1)[row] = v;
  }
}

// ---------------------------------------------------------------------------
// LayerNorm over C=768, one block (256 thr) per row, bf16 output.
// ---------------------------------------------------------------------------
__device__ __forceinline__ void ln_body(const float* __restrict__ x, const float* __restrict__ w,
                                        const float* __restrict__ b, u16* __restrict__ out, int row) {
  const int t = threadIdx.x;
  const float* xr = x + (size_t)row * CC;
  float v0 = xr[t], v1 = xr[t + 256], v2 = xr[t + 512];
  float s = v0 + v1 + v2;
  float ss = v0 * v0 + v1 * v1 + v2 * v2;
  #pragma unroll
  for (int o = 32; o > 0; o >>= 1) {
    s += __shfl_xor(s, o, 64);
    ss += __shfl_xor(ss, o, 64);
  }
  __shared__ float rs[4], rss[4];
  const int wv = t >> 6, ln = t & 63;
  if (ln == 0) { rs[wv] = s; rss[wv] = ss; }
  __syncthreads();
  s = rs[0] + rs[1] + rs[2] + rs[3];
  ss = rss[0] + rss[1] + rss[2] + rss[3];
  const float mu = s * (1.f / 768.f);
  const float var = ss * (1.f / 768.f) - mu * mu;
  const float rstd = rsqrtf(var + 1e-6f);
  u16* orow = out + (size_t)row * CC;
  orow[t]       = f2bf((v0 - mu) * rstd * w[t]       + b[t]);
  orow[t + 256] = f2bf((v1 - mu) * rstd * w[t + 256] + b[t + 256]);
  orow[t + 512] = f2bf((v2 - mu) * rstd * w[t + 512] + b[t + 512]);
}

__global__ __launch_bounds__(256)
void ln_to_bf16(const float* __restrict__ x, const float* __restrict__ w,
                const float* __restrict__ b, u16* __restrict__ out) {
  ln_body(x, w, b, out, blockIdx.x);
}

__global__ __launch_bounds__(256)
void ln3_to_bf16(const float* __restrict__ x0, const float* __restrict__ w0, const float* __restrict__ b0, u16* __restrict__ o0,
                 const float* __restrict__ x1, const float* __restrict__ w1, const float* __restrict__ b1, u16* __restrict__ o1,
                 const float* __restrict__ x2, const float* __restrict__ w2, const float* __restrict__ b2, u16* __restrict__ o2) {
  const int sel = blockIdx.y;
  const float* x = (sel == 0) ? x0 : (sel == 1) ? x1 : x2;
  const float* w = (sel == 0) ? w0 : (sel == 1) ? w1 : w2;
  const float* b = (sel == 0) ? b0 : (sel == 1) ? b1 : b2;
  u16* o = (sel == 0) ? o0 : (sel == 1) ? o1 : o2;
  ln_body(x, w, b, o, blockIdx.x);
}

// ---------------------------------------------------------------------------
// bf16 MFMA GEMM core v2: TM x 64 tile, BK=64 staged as two 32-col panels
// (keeps global_load_lds wave-contiguous; fragment-read bank pattern same as
// BK=32 row-major). 4 waves: each computes (TM/2) x 32 via FI x 2 frags.
// MODE 0: bf16 out; MODE 1: f32 out; MODE 2: f32 out = res + gamma[n]*(acc+bias)
// ---------------------------------------------------------------------------
template <int TM, int MODE>
__device__ __forceinline__ void gemm_core(const u16* __restrict__ A, const u16* __restrict__ W,
                                          const float* __restrict__ bias, void* __restrict__ outv,
                                          const float* __restrict__ res, const float* __restrict__ gamma,
                                          int N, int K, int m0, int n0) {
  constexpr int FI = TM / 32;   // M-frags per wave (4 for TM=128, 2 for TM=64)
  constexpr int NIA = TM / 32;  // A-staging glds insts per thread
  __shared__ u16 As[TM * 64];   // [2 panels][TM][32]
  __shared__ u16 Bs[64 * 64];   // [2 panels][64][32]
  const int tid = threadIdx.x;
  const int wv = tid >> 6, lane = tid & 63;
  const int quad = lane >> 4, l16 = lane & 15;
  const int wm = wv & 1, wn = wv >> 1;
  const int sr4 = lane >> 2;        // staging row within 16-row chunk
  const int sc = (lane & 3) << 3;   // staging col elem within 32-col panel

  f32x4 acc[FI][2];
  #pragma unroll
  for (int i = 0; i < FI; ++i)
    #pragma unroll
    for (int j = 0; j < 2; ++j)
      acc[i][j] = (f32x4){0.f, 0.f, 0.f, 0.f};

  for (int k0 = 0; k0 < K; k0 += 64) {
    __syncthreads();
    #pragma unroll
    for (int j = 0; j < NIA; ++j) {
      const int g = wv * NIA + j;
      const int p = g & 1, rb = g >> 1;  // panel, 16-row block
      gl_lds16(A + (size_t)(m0 + rb * 16 + sr4) * K + (k0 + p * 32 + sc),
               (char*)As + p * (TM * 64) + rb * 1024 + lane * 16);
    }
    #pragma unroll
    for (int j = 0; j < 2; ++j) {
      const int g = wv * 2 + j;
      const int p = g & 1, rb = g >> 1;
      gl_lds16(W + (size_t)(n0 + rb * 16 + sr4) * K + (k0 + p * 32 + sc),
               (char*)Bs + p * 4096 + rb * 1024 + lane * 16);
    }
    __syncthreads();
    #pragma unroll
    for (int kk = 0; kk < 2; ++kk) {
      bf16x8 af[FI], bfr[2];
      #pragma unroll
      for (int i = 0; i < FI; ++i)
        af[i] = *(const bf16x8*)(As + kk * (TM * 32) + (wm * (TM / 2) + i * 16 + l16) * 32 + quad * 8);
      #pragma unroll
      for (int j = 0; j < 2; ++j)
        bfr[j] = *(const bf16x8*)(Bs + kk * 2048 + (wn * 32 + j * 16 + l16) * 32 + quad * 8);
      #pragma unroll
      for (int i = 0; i < FI; ++i)
        #pragma unroll
        for (int j = 0; j < 2; ++j)
          acc[i][j] = __builtin_amdgcn_mfma_f32_16x16x32_bf16(af[i], bfr[j], acc[i][j], 0, 0, 0);
    }
  }

  #pragma unroll
  for (int i = 0; i < FI; ++i) {
    #pragma unroll
    for (int j = 0; j < 2; ++j) {
      const int col = n0 + wn * 32 + j * 16 + l16;
      const float bs = bias[col];
      #pragma unroll
      for (int r = 0; r < 4; ++r) {
        const int row = m0 + wm * (TM / 2) + i * 16 + quad * 4 + r;
        const float v = acc[i][j][r] + bs;
        const size_t o = (size_t)row * N + col;
        if (MODE == 0) ((u16*)outv)[o] = f2bf(v);
        else if (MODE == 1) ((float*)outv)[o] = v;
        else ((float*)outv)[o] = res[o] + gamma[col] * v;
      }
    }
  }
}

template <int MODE>
__global__ __launch_bounds__(256, 5)
void gemm_bt(const u16* __restrict__ A, const u16* __restrict__ W,
             const float* __restrict__ bias, void* __restrict__ outv,
             const float* __restrict__ res, const float* __restrict__ gamma,
             int N, int K) {
  gemm_core<128, MODE>(A, W, bias, outv, res, gamma, N, K, blockIdx.x * 128, blockIdx.y * 64);
}

__global__ __launch_bounds__(256, 5)
void gemm_val_dual(const u16* __restrict__ A0, const u16* __restrict__ W0, const float* __restrict__ b0, u16* __restrict__ o0,
                   const u16* __restrict__ A1, const u16* __restrict__ W1, const float* __restrict__ b1, u16* __restrict__ o1,
                   int N, int K) {
  const int z = blockIdx.z;
  const u16* A = z ? A1 : A0;
  const u16* W = z ? W1 : W0;
  const float* b = z ? b1 : b0;
  u16* o = z ? o1 : o0;
  gemm_core<128, 0>(A, W, b, (void*)o, nullptr, nullptr, N, K, blockIdx.x * 128, blockIdx.y * 64);
}

// Small GEMM [M,K]x[128,K]^T -> f32: 64x64 tile, grid (M/64, 2).
__global__ __launch_bounds__(256, 5)
void gemm_small(const u16* __restrict__ A, const u16* __restrict__ W,
                const float* __restrict__ bias, float* __restrict__ out,
                int N, int K) {
  gemm_core<64, 1>(A, W, bias, (void*)out, nullptr, nullptr, N, K, blockIdx.x * 64, blockIdx.y * 64);
}

// ---------------------------------------------------------------------------
// Deformable sampling: 16 lanes per (q,h), each lane 8 channels (dwordx4).
// Predicated OOB (clamp idx, zero weight).
// ---------------------------------------------------------------------------
__global__ __launch_bounds__(256)
void msds_sample(const u16* __restrict__ value, const float* __restrict__ offaw,
                 const float* __restrict__ ref, u16* __restrict__ out) {
  const int t = blockIdx.x * 256 + threadIdx.x;
  const int pi = t >> 4;
  const int gl = t & 15;
  const int q = pi / NH;
  const int h = pi - q * NH;
  const float* oa = offaw + (size_t)q * 128;
  const float rx = ref[q * 2] * (float)WW - 0.5f;
  const float ry = ref[q * 2 + 1] * (float)HH - 0.5f;

  const float lg0 = oa[48 + h * 4 + 0], lg1 = oa[48 + h * 4 + 1];
  const float lg2 = oa[48 + h * 4 + 2], lg3 = oa[48 + h * 4 + 3];
  const float mx = fmaxf(fmaxf(lg0, lg1), fmaxf(lg2, lg3));
  const float e0 = __expf(lg0 - mx), e1 = __expf(lg1 - mx);
  const float e2 = __expf(lg2 - mx), e3 = __expf(lg3 - mx);
  const float inv = 1.f / (e0 + e1 + e2 + e3);
  const float wp[4] = {e0 * inv, e1 * inv, e2 * inv, e3 * inv};

  float acc[8];
  #pragma unroll
  for (int k = 0; k < 8; ++k) acc[k] = 0.f;

  const u16* vbase = value + h * DH + gl * 8;
  #pragma unroll
  for (int p = 0; p < 4; ++p) {
    const float px = rx + oa[h * 8 + p * 2];
    const float py = ry + oa[h * 8 + p * 2 + 1];
    const float fxf = floorf(px), fyf = floorf(py);
    const int x0 = (int)fxf, y0 = (int)fyf;
    const float fx = px - fxf, fy = py - fyf;
    const float cw[4] = {wp[p] * (1.f - fy) * (1.f - fx), wp[p] * (1.f - fy) * fx,
                         wp[p] * fy * (1.f - fx),         wp[p] * fy * fx};
    #pragma unroll
    for (int c = 0; c < 4; ++c) {
      const int yy = y0 + (c >> 1);
      const int xx = x0 + (c & 1);
      const bool valid = (yy >= 0) & (yy < HH) & (xx >= 0) & (xx < WW);
      const int yc = min(max(yy, 0), HH - 1);
      const int xc = min(max(xx, 0), WW - 1);
      const float w2 = valid ? cw[c] : 0.f;
      const u32x4 u = *(const u32x4*)(vbase + (size_t)(yc * WW + xc) * CC);
      #pragma unroll
      for (int k = 0; k < 4; ++k) {
        acc[2 * k]     += w2 * u2f(u[k] << 16);
        acc[2 * k + 1] += w2 * u2f(u[k] & 0xffff0000u);
      }
    }
  }
  u32x4 o;
  #pragma unroll
  for (int k = 0; k < 4; ++k)
    o[k] = (u32)f2bf(acc[2 * k]) | ((u32)f2bf(acc[2 * k + 1]) << 16);
  *(u32x4*)(out + (size_t)q * CC + h * DH + gl * 8) = o;
}

// ---------------------------------------------------------------------------
extern "C" void kernel_launch(void* const* d_in, const int* in_sizes, int n_in,
                              void* d_out, int out_size, void* d_ws, size_t ws_size,
                              hipStream_t stream) {
  const float* query = (const float*)d_in[0];
  const float* refp  = (const float*)d_in[1];
  const float* feat  = (const float*)d_in[2];
  const float* feat2 = (const float*)d_in[3];
  const float* qn_w = (const float*)d_in[6];
  const float* qn_b = (const float*)d_in[7];
  const float* fn_w = (const float*)d_in[8];
  const float* fn_b = (const float*)d_in[9];
  const float* so_w = (const float*)d_in[10];
  const float* so_b = (const float*)d_in[11];
  const float* aw_w = (const float*)d_in[12];
  const float* aw_b = (const float*)d_in[13];
  const float* vp_w = (const float*)d_in[14];
  const float* vp_b = (const float*)d_in[15];
  const float* op_w = (const float*)d_in[16];
  const float* op_b = (const float*)d_in[17];
  const float* gamma = (const float*)d_in[18];
  const float* qn2_w = (const float*)d_in[19];
  const float* qn2_b = (const float*)d_in[20];
  const float* fn2_w = (const float*)d_in[21];
  const float* fn2_b = (const float*)d_in[22];
  const float* so2_w = (const float*)d_in[23];
  const float* so2_b = (const float*)d_in[24];
  const float* aw2_w = (const float*)d_in[25];
  const float* aw2_b = (const float*)d_in[26];
  const float* vp2_w = (const float*)d_in[27];
  const float* vp2_b = (const float*)d_in[28];
  const float* op2_w = (const float*)d_in[29];
  const float* op2_b = (const float*)d_in[30];
  const float* gamma2 = (const float*)d_in[31];

  char* ws = (char*)d_ws;
  size_t off = 0;
  auto alloc = [&](size_t bytes) -> void* {
    void* p = ws + off;
    off += (bytes + 255) & ~(size_t)255;
    return p;
  };
  u16* w4    = (u16*)alloc((size_t)4 * 589824 * 2);
  u16* cat1  = (u16*)alloc((size_t)98304 * 2);
  u16* cat2  = (u16*)alloc((size_t)98304 * 2);
  float* b1  = (float*)alloc(128 * 4);
  float* b2  = (float*)alloc(128 * 4);
  u16* qn    = (u16*)alloc((size_t)LQ * CC * 2);  // reused as qn2
  u16* fn    = (u16*)alloc((size_t)LQ * CC * 2);  // reused as a_pre
  u16* fn2   = (u16*)alloc((size_t)LQ * CC * 2);  // reused as a2_pre
  u16* val1  = (u16*)alloc((size_t)LQ * CC * 2);
  u16* val2  = (u16*)alloc((size_t)LQ * CC * 2);
  float* offaw = (float*)alloc((size_t)LQ * 128 * 4);  // both rounds
  float* qbuf  = (float*)alloc((size_t)LQ * CC * 4);

  dim3 blk(256);
  dim3 gbig(LQ / 128, CC / 64), gdual(LQ / 128, CC / 64, 2), gsm(LQ / 64, 2);

  prep_weights<<<9985, blk, 0, stream>>>(vp_w, op_w, vp2_w, op2_w, so_w, aw_w, so2_w, aw2_w,
                                         so_b, aw_b, so2_b, aw2_b, w4, cat1, cat2, b1, b2);
  ln3_to_bf16<<<dim3(LQ, 3), blk, 0, stream>>>(query, qn_w, qn_b, qn,
                                               feat, fn_w, fn_b, fn,
                                               feat2, fn2_w, fn2_b, fn2);
  gemm_val_dual<<<gdual, blk, 0, stream>>>(fn, w4, vp_b, val1,
                                           fn2, w4 + 2 * 589824, vp2_b, val2, CC, CC);
  gemm_small<<<gsm, blk, 0, stream>>>(qn, cat1, b1, offaw, 128, CC);
  msds_sample<<<LQ * NH / 16, blk, 0, stream>>>(val1, offaw, refp, fn);  // a_pre -> fn
  gemm_bt<2><<<gbig, blk, 0, stream>>>(fn, w4 + 589824, op_b, (void*)qbuf, query, gamma, CC, CC);
  ln_to_bf16<<<LQ, blk, 0, stream>>>(qbuf, qn2_w, qn2_b, qn);  // qn2 -> qn
  gemm_small<<<gsm, blk, 0, stream>>>(qn, cat2, b2, offaw, 128, CC);
  msds_sample<<<LQ * NH / 16, blk, 0, stream>>>(val2, offaw, refp, fn2);  // a2_pre -> fn2
  gemm_bt<2><<<gbig, blk, 0, stream>>>(fn2, w4 + 3 * 589824, op2_b, d_out, qbuf, gamma2, CC, CC);
}

// Round 4
// 333.913 us; speedup vs baseline: 1.3536x; 1.0243x over previous
//
#include <hip/hip_runtime.h>
#include <hip/hip_bf16.h>

typedef unsigned short u16;
typedef unsigned int u32;
typedef __attribute__((ext_vector_type(8))) short bf16x8;
typedef __attribute__((ext_vector_type(4))) float f32x4;
typedef __attribute__((ext_vector_type(4))) u32 u32x4;
typedef __attribute__((ext_vector_type(2))) u32 u32x2;

#define LQ 9216
#define CC 768
#define NH 6
#define DH 128
#define HH 96
#define WW 96

__device__ __forceinline__ u16 f2bf(float f) {
  union { float f; u32 u; } x; x.f = f;
  u32 r = x.u + 0x7fff + ((x.u >> 16) & 1);
  return (u16)(r >> 16);
}
__device__ __forceinline__ float u2f(u32 u) {
  union { u32 u; float f; } x; x.u = u; return x.f;
}

__device__ __forceinline__ void gl_lds16(const void* g, void* l) {
  __builtin_amdgcn_global_load_lds((const __attribute__((address_space(1))) void*)g,
                                   (__attribute__((address_space(3))) void*)l, 16, 0, 0);
}

// ---------------------------------------------------------------------------
// Weight prep: fp32 -> bf16 for the four 768x768 mats; build zero-padded
// [128,768] concat(so_w, aw_w) mats + padded [128] biases.
// ---------------------------------------------------------------------------
__global__ __launch_bounds__(256)
void prep_weights(const float* __restrict__ vp, const float* __restrict__ op,
                  const float* __restrict__ vp2, const float* __restrict__ op2,
                  const float* __restrict__ so, const float* __restrict__ aw,
                  const float* __restrict__ so2, const float* __restrict__ aw2,
                  const float* __restrict__ so_b, const float* __restrict__ aw_b,
                  const float* __restrict__ so2_b, const float* __restrict__ aw2_b,
                  u16* __restrict__ w4, u16* __restrict__ cat1, u16* __restrict__ cat2,
                  float* __restrict__ b1, float* __restrict__ b2) {
  const int i = blockIdx.x * 256 + threadIdx.x;
  const int NW = 589824;
  if (i < 4 * NW) {
    const int m = i / NW, r = i - m * NW;
    const float* s = (m == 0) ? vp : (m == 1) ? op : (m == 2) ? vp2 : op2;
    w4[i] = f2bf(s[r]);
  } else if (i < 4 * NW + 2 * 98304) {
    const int j = i - 4 * NW;
    const int which = j / 98304;
    const int r = j - which * 98304;
    const int row = r / 768, colr = r - row * 768;
    float v = 0.f;
    if (row < 48) v = (which ? so2 : so)[row * 768 + colr];
    else if (row < 72) v = (which ? aw2 : aw)[(row - 48) * 768 + colr];
    (which ? cat2 : cat1)[r] = f2bf(v);
  } else if (i < 4 * NW + 2 * 98304 + 256) {
    const int j = i - 4 * NW - 2 * 98304;
    const int which = j >> 7, row = j & 127;
    float v = 0.f;
    if (row < 48) v = (which ? so2_b : so_b)[row];
    else if (row < 72) v = (which ? aw2_b : aw_b)[row - 48];
    (which ? b2 : b1)[row] = v;
  }
}

// ---------------------------------------------------------------------------
// Wave-per-row LayerNorm: 64 lanes x 3 float4 = 768 elems; shuffle-only
// reduction; packed bf16x4 (u32x2) stores. 4 rows per 256-thread block.
// ---------------------------------------------------------------------------
__device__ __forceinline__ void ln_wave_body(const float* __restrict__ x, const float* __restrict__ w,
                                             const float* __restrict__ b, u16* __restrict__ out, int row) {
  const int lane = threadIdx.x & 63;
  const float4* xr = (const float4*)(x + (size_t)row * CC);
  float4 v[3];
  #pragma unroll
  for (int j = 0; j < 3; ++j) v[j] = xr[lane + 64 * j];
  float s = 0.f, ss = 0.f;
  #pragma unroll
  for (int j = 0; j < 3; ++j) {
    s += v[j].x + v[j].y + v[j].z + v[j].w;
    ss += v[j].x * v[j].x + v[j].y * v[j].y + v[j].z * v[j].z + v[j].w * v[j].w;
  }
  #pragma unroll
  for (int o = 32; o > 0; o >>= 1) {
    s += __shfl_xor(s, o, 64);
    ss += __shfl_xor(ss, o, 64);
  }
  const float mu = s * (1.f / 768.f);
  const float var = ss * (1.f / 768.f) - mu * mu;
  const float rstd = rsqrtf(var + 1e-6f);
  const float4* wr = (const float4*)w;
  const float4* br = (const float4*)b;
  u32x2* orow = (u32x2*)(out + (size_t)row * CC);
  #pragma unroll
  for (int j = 0; j < 3; ++j) {
    const float4 wv = wr[lane + 64 * j];
    const float4 bv = br[lane + 64 * j];
    const float r0 = (v[j].x - mu) * rstd * wv.x + bv.x;
    const float r1 = (v[j].y - mu) * rstd * wv.y + bv.y;
    const float r2 = (v[j].z - mu) * rstd * wv.z + bv.z;
    const float r3 = (v[j].w - mu) * rstd * wv.w + bv.w;
    u32x2 o;
    o[0] = (u32)f2bf(r0) | ((u32)f2bf(r1) << 16);
    o[1] = (u32)f2bf(r2) | ((u32)f2bf(r3) << 16);
    orow[lane + 64 * j] = o;
  }
}

__global__ __launch_bounds__(256)
void ln_to_bf16(const float* __restrict__ x, const float* __restrict__ w,
                const float* __restrict__ b, u16* __restrict__ out) {
  const int row = blockIdx.x * 4 + (threadIdx.x >> 6);
  ln_wave_body(x, w, b, out, row);
}

__global__ __launch_bounds__(256)
void ln3_to_bf16(const float* __restrict__ x0, const float* __restrict__ w0, const float* __restrict__ b0, u16* __restrict__ o0,
                 const float* __restrict__ x1, const float* __restrict__ w1, const float* __restrict__ b1, u16* __restrict__ o1,
                 const float* __restrict__ x2, const float* __restrict__ w2, const float* __restrict__ b2, u16* __restrict__ o2) {
  const int sel = blockIdx.y;
  const float* x = (sel == 0) ? x0 : (sel == 1) ? x1 : x2;
  const float* w = (sel == 0) ? w0 : (sel == 1) ? w1 : w2;
  const float* b = (sel == 0) ? b0 : (sel == 1) ? b1 : b2;
  u16* o = (sel == 0) ? o0 : (sel == 1) ? o1 : o2;
  const int row = blockIdx.x * 4 + (threadIdx.x >> 6);
  ln_wave_body(x, w, b, o, row);
}

// ---------------------------------------------------------------------------
// bf16 MFMA GEMM core v2: TM x 64 tile, BK=64 staged as two 32-col panels.
// 4 waves: each computes (TM/2) x 32 via FI x 2 frags.
// MODE 0: bf16 out; MODE 1: f32 out; MODE 2: f32 out = res + gamma[n]*(acc+bias)
// ---------------------------------------------------------------------------
template <int TM, int MODE>
__device__ __forceinline__ void gemm_core(const u16* __restrict__ A, const u16* __restrict__ W,
                                          const float* __restrict__ bias, void* __restrict__ outv,
                                          const float* __restrict__ res, const float* __restrict__ gamma,
                                          int N, int K, int m0, int n0) {
  constexpr int FI = TM / 32;
  constexpr int NIA = TM / 32;
  __shared__ u16 As[TM * 64];
  __shared__ u16 Bs[64 * 64];
  const int tid = threadIdx.x;
  const int wv = tid >> 6, lane = tid & 63;
  const int quad = lane >> 4, l16 = lane & 15;
  const int wm = wv & 1, wn = wv >> 1;
  const int sr4 = lane >> 2;
  const int sc = (lane & 3) << 3;

  f32x4 acc[FI][2];
  #pragma unroll
  for (int i = 0; i < FI; ++i)
    #pragma unroll
    for (int j = 0; j < 2; ++j)
      acc[i][j] = (f32x4){0.f, 0.f, 0.f, 0.f};

  for (int k0 = 0; k0 < K; k0 += 64) {
    __syncthreads();
    #pragma unroll
    for (int j = 0; j < NIA; ++j) {
      const int g = wv * NIA + j;
      const int p = g & 1, rb = g >> 1;
      gl_lds16(A + (size_t)(m0 + rb * 16 + sr4) * K + (k0 + p * 32 + sc),
               (char*)As + p * (TM * 64) + rb * 1024 + lane * 16);
    }
    #pragma unroll
    for (int j = 0; j < 2; ++j) {
      const int g = wv * 2 + j;
      const int p = g & 1, rb = g >> 1;
      gl_lds16(W + (size_t)(n0 + rb * 16 + sr4) * K + (k0 + p * 32 + sc),
               (char*)Bs + p * 4096 + rb * 1024 + lane * 16);
    }
    __syncthreads();
    #pragma unroll
    for (int kk = 0; kk < 2; ++kk) {
      bf16x8 af[FI], bfr[2];
      #pragma unroll
      for (int i = 0; i < FI; ++i)
        af[i] = *(const bf16x8*)(As + kk * (TM * 32) + (wm * (TM / 2) + i * 16 + l16) * 32 + quad * 8);
      #pragma unroll
      for (int j = 0; j < 2; ++j)
        bfr[j] = *(const bf16x8*)(Bs + kk * 2048 + (wn * 32 + j * 16 + l16) * 32 + quad * 8);
      #pragma unroll
      for (int i = 0; i < FI; ++i)
        #pragma unroll
        for (int j = 0; j < 2; ++j)
          acc[i][j] = __builtin_amdgcn_mfma_f32_16x16x32_bf16(af[i], bfr[j], acc[i][j], 0, 0, 0);
    }
  }

  #pragma unroll
  for (int i = 0; i < FI; ++i) {
    #pragma unroll
    for (int j = 0; j < 2; ++j) {
      const int col = n0 + wn * 32 + j * 16 + l16;
      const float bs = bias[col];
      #pragma unroll
      for (int r = 0; r < 4; ++r) {
        const int row = m0 + wm * (TM / 2) + i * 16 + quad * 4 + r;
        const float v = acc[i][j][r] + bs;
        const size_t o = (size_t)row * N + col;
        if (MODE == 0) ((u16*)outv)[o] = f2bf(v);
        else if (MODE == 1) ((float*)outv)[o] = v;
        else ((float*)outv)[o] = res[o] + gamma[col] * v;
      }
    }
  }
}

template <int MODE>
__global__ __launch_bounds__(256, 5)
void gemm_bt(const u16* __restrict__ A, const u16* __restrict__ W,
             const float* __restrict__ bias, void* __restrict__ outv,
             const float* __restrict__ res, const float* __restrict__ gamma,
             int N, int K) {
  gemm_core<128, MODE>(A, W, bias, outv, res, gamma, N, K, blockIdx.x * 128, blockIdx.y * 64);
}

__global__ __launch_bounds__(256, 5)
void gemm_val_dual(const u16* __restrict__ A0, const u16* __restrict__ W0, const float* __restrict__ b0, u16* __restrict__ o0,
                   const u16* __restrict__ A1, const u16* __restrict__ W1, const float* __restrict__ b1, u16* __restrict__ o1,
                   int N, int K) {
  const int z = blockIdx.z;
  const u16* A = z ? A1 : A0;
  const u16* W = z ? W1 : W0;
  const float* b = z ? b1 : b0;
  u16* o = z ? o1 : o0;
  gemm_core<128, 0>(A, W, b, (void*)o, nullptr, nullptr, N, K, blockIdx.x * 128, blockIdx.y * 64);
}

__global__ __launch_bounds__(256, 5)
void gemm_small(const u16* __restrict__ A, const u16* __restrict__ W,
                const float* __restrict__ bias, float* __restrict__ out,
                int N, int K) {
  gemm_core<64, 1>(A, W, bias, (void*)out, nullptr, nullptr, N, K, blockIdx.x * 64, blockIdx.y * 64);
}

// ---------------------------------------------------------------------------
// Deformable sampling: 16 lanes per (q,h), each lane 8 channels (dwordx4).
// Predicated OOB (clamp idx, zero weight).
// ---------------------------------------------------------------------------
__global__ __launch_bounds__(256)
void msds_sample(const u16* __restrict__ value, const float* __restrict__ offaw,
                 const float* __restrict__ ref, u16* __restrict__ out) {
  const int t = blockIdx.x * 256 + threadIdx.x;
  const int pi = t >> 4;
  const int gl = t & 15;
  const int q = pi / NH;
  const int h = pi - q * NH;
  const float* oa = offaw + (size_t)q * 128;
  const float rx = ref[q * 2] * (float)WW - 0.5f;
  const float ry = ref[q * 2 + 1] * (float)HH - 0.5f;

  const float lg0 = oa[48 + h * 4 + 0], lg1 = oa[48 + h * 4 + 1];
  const float lg2 = oa[48 + h * 4 + 2], lg3 = oa[48 + h * 4 + 3];
  const float mx = fmaxf(fmaxf(lg0, lg1), fmaxf(lg2, lg3));
  const float e0 = __expf(lg0 - mx), e1 = __expf(lg1 - mx);
  const float e2 = __expf(lg2 - mx), e3 = __expf(lg3 - mx);
  const float inv = 1.f / (e0 + e1 + e2 + e3);
  const float wp[4] = {e0 * inv, e1 * inv, e2 * inv, e3 * inv};

  float acc[8];
  #pragma unroll
  for (int k = 0; k < 8; ++k) acc[k] = 0.f;

  const u16* vbase = value + h * DH + gl * 8;
  #pragma unroll
  for (int p = 0; p < 4; ++p) {
    const float px = rx + oa[h * 8 + p * 2];
    const float py = ry + oa[h * 8 + p * 2 + 1];
    const float fxf = floorf(px), fyf = floorf(py);
    const int x0 = (int)fxf, y0 = (int)fyf;
    const float fx = px - fxf, fy = py - fyf;
    const float cw[4] = {wp[p] * (1.f - fy) * (1.f - fx), wp[p] * (1.f - fy) * fx,
                         wp[p] * fy * (1.f - fx),         wp[p] * fy * fx};
    #pragma unroll
    for (int c = 0; c < 4; ++c) {
      const int yy = y0 + (c >> 1);
      const int xx = x0 + (c & 1);
      const bool valid = (yy >= 0) & (yy < HH) & (xx >= 0) & (xx < WW);
      const int yc = min(max(yy, 0), HH - 1);
      const int xc = min(max(xx, 0), WW - 1);
      const float w2 = valid ? cw[c] : 0.f;
      const u32x4 u = *(const u32x4*)(vbase + (size_t)(yc * WW + xc) * CC);
      #pragma unroll
      for (int k = 0; k < 4; ++k) {
        acc[2 * k]     += w2 * u2f(u[k] << 16);
        acc[2 * k + 1] += w2 * u2f(u[k] & 0xffff0000u);
      }
    }
  }
  u32x4 o;
  #pragma unroll
  for (int k = 0; k < 4; ++k)
    o[k] = (u32)f2bf(acc[2 * k]) | ((u32)f2bf(acc[2 * k + 1]) << 16);
  *(u32x4*)(out + (size_t)q * CC + h * DH + gl * 8) = o;
}

// ---------------------------------------------------------------------------
extern "C" void kernel_launch(void* const* d_in, const int* in_sizes, int n_in,
                              void* d_out, int out_size, void* d_ws, size_t ws_size,
                              hipStream_t stream) {
  const float* query = (const float*)d_in[0];
  const float* refp  = (const float*)d_in[1];
  const float* feat  = (const float*)d_in[2];
  const float* feat2 = (const float*)d_in[3];
  const float* qn_w = (const float*)d_in[6];
  const float* qn_b = (const float*)d_in[7];
  const float* fn_w = (const float*)d_in[8];
  const float* fn_b = (const float*)d_in[9];
  const float* so_w = (const float*)d_in[10];
  const float* so_b = (const float*)d_in[11];
  const float* aw_w = (const float*)d_in[12];
  const float* aw_b = (const float*)d_in[13];
  const float* vp_w = (const float*)d_in[14];
  const float* vp_b = (const float*)d_in[15];
  const float* op_w = (const float*)d_in[16];
  const float* op_b = (const float*)d_in[17];
  const float* gamma = (const float*)d_in[18];
  const float* qn2_w = (const float*)d_in[19];
  const float* qn2_b = (const float*)d_in[20];
  const float* fn2_w = (const float*)d_in[21];
  const float* fn2_b = (const float*)d_in[22];
  const float* so2_w = (const float*)d_in[23];
  const float* so2_b = (const float*)d_in[24];
  const float* aw2_w = (const float*)d_in[25];
  const float* aw2_b = (const float*)d_in[26];
  const float* vp2_w = (const float*)d_in[27];
  const float* vp2_b = (const float*)d_in[28];
  const float* op2_w = (const float*)d_in[29];
  const float* op2_b = (const float*)d_in[30];
  const float* gamma2 = (const float*)d_in[31];

  char* ws = (char*)d_ws;
  size_t off = 0;
  auto alloc = [&](size_t bytes) -> void* {
    void* p = ws + off;
    off += (bytes + 255) & ~(size_t)255;
    return p;
  };
  u16* w4    = (u16*)alloc((size_t)4 * 589824 * 2);
  u16* cat1  = (u16*)alloc((size_t)98304 * 2);
  u16* cat2  = (u16*)alloc((size_t)98304 * 2);
  float* b1  = (float*)alloc(128 * 4);
  float* b2  = (float*)alloc(128 * 4);
  u16* qn    = (u16*)alloc((size_t)LQ * CC * 2);  // reused as qn2
  u16* fn    = (u16*)alloc((size_t)LQ * CC * 2);  // reused as a_pre
  u16* fn2   = (u16*)alloc((size_t)LQ * CC * 2);  // reused as a2_pre
  u16* val1  = (u16*)alloc((size_t)LQ * CC * 2);
  u16* val2  = (u16*)alloc((size_t)LQ * CC * 2);
  float* offaw = (float*)alloc((size_t)LQ * 128 * 4);  // both rounds
  float* qbuf  = (float*)alloc((size_t)LQ * CC * 4);

  dim3 blk(256);
  dim3 gbig(LQ / 128, CC / 64), gdual(LQ / 128, CC / 64, 2), gsm(LQ / 64, 2);

  prep_weights<<<9985, blk, 0, stream>>>(vp_w, op_w, vp2_w, op2_w, so_w, aw_w, so2_w, aw2_w,
                                         so_b, aw_b, so2_b, aw2_b, w4, cat1, cat2, b1, b2);
  ln3_to_bf16<<<dim3(LQ / 4, 3), blk, 0, stream>>>(query, qn_w, qn_b, qn,
                                                   feat, fn_w, fn_b, fn,
                                                   feat2, fn2_w, fn2_b, fn2);
  gemm_val_dual<<<gdual, blk, 0, stream>>>(fn, w4, vp_b, val1,
                                           fn2, w4 + 2 * 589824, vp2_b, val2, CC, CC);
  gemm_small<<<gsm, blk, 0, stream>>>(qn, cat1, b1, offaw, 128, CC);
  msds_sample<<<LQ * NH / 16, blk, 0, stream>>>(val1, offaw, refp, fn);  // a_pre -> fn
  gemm_bt<2><<<gbig, blk, 0, stream>>>(fn, w4 + 589824, op_b, (void*)qbuf, query, gamma, CC, CC);
  ln_to_bf16<<<LQ / 4, blk, 0, stream>>>(qbuf, qn2_w, qn2_b, qn);  // qn2 -> qn
  gemm_small<<<gsm, blk, 0, stream>>>(qn, cat2, b2, offaw, 128, CC);
  msds_sample<<<LQ * NH / 16, blk, 0, stream>>>(val2, offaw, refp, fn2);  // a2_pre -> fn2
  gemm_bt<2><<<gbig, blk, 0, stream>>>(fn2, w4 + 3 * 589824, op2_b, d_out, qbuf, gamma2, CC, CC);
}

// Round 5
// 318.770 us; speedup vs baseline: 1.4179x; 1.0475x over previous
//
#include <hip/hip_runtime.h>
#include <hip/hip_bf16.h>

typedef unsigned short u16;
typedef unsigned int u32;
typedef __attribute__((ext_vector_type(8))) short bf16x8;
typedef __attribute__((ext_vector_type(4))) float f32x4;
typedef __attribute__((ext_vector_type(4))) u32 u32x4;
typedef __attribute__((ext_vector_type(2))) u32 u32x2;

#define LQ 9216
#define CC 768
#define NH 6
#define DH 128
#define HH 96
#define WW 96

__device__ __forceinline__ u16 f2bf(float f) {
  union { float f; u32 u; } x; x.f = f;
  u32 r = x.u + 0x7fff + ((x.u >> 16) & 1);
  return (u16)(r >> 16);
}
__device__ __forceinline__ float u2f(u32 u) {
  union { u32 u; float f; } x; x.u = u; return x.f;
}
__device__ __forceinline__ float bf2f(u16 u) { return u2f(((u32)u) << 16); }

__device__ __forceinline__ void gl_lds16(const void* g, void* l) {
  __builtin_amdgcn_global_load_lds((const __attribute__((address_space(1))) void*)g,
                                   (__attribute__((address_space(3))) void*)l, 16, 0, 0);
}

// ---------------------------------------------------------------------------
// Wave-per-row LayerNorm body (f32 input): 64 lanes x 3 float4.
// ---------------------------------------------------------------------------
__device__ __forceinline__ void ln_wave_body(const float* __restrict__ x, const float* __restrict__ w,
                                             const float* __restrict__ b, u16* __restrict__ out, int row) {
  const int lane = threadIdx.x & 63;
  const float4* xr = (const float4*)(x + (size_t)row * CC);
  float4 v[3];
  #pragma unroll
  for (int j = 0; j < 3; ++j) v[j] = xr[lane + 64 * j];
  float s = 0.f, ss = 0.f;
  #pragma unroll
  for (int j = 0; j < 3; ++j) {
    s += v[j].x + v[j].y + v[j].z + v[j].w;
    ss += v[j].x * v[j].x + v[j].y * v[j].y + v[j].z * v[j].z + v[j].w * v[j].w;
  }
  #pragma unroll
  for (int o = 32; o > 0; o >>= 1) {
    s += __shfl_xor(s, o, 64);
    ss += __shfl_xor(ss, o, 64);
  }
  const float mu = s * (1.f / 768.f);
  const float var = ss * (1.f / 768.f) - mu * mu;
  const float rstd = rsqrtf(var + 1e-6f);
  const float4* wr = (const float4*)w;
  const float4* br = (const float4*)b;
  u32x2* orow = (u32x2*)(out + (size_t)row * CC);
  #pragma unroll
  for (int j = 0; j < 3; ++j) {
    const float4 wv = wr[lane + 64 * j];
    const float4 bv = br[lane + 64 * j];
    const float r0 = (v[j].x - mu) * rstd * wv.x + bv.x;
    const float r1 = (v[j].y - mu) * rstd * wv.y + bv.y;
    const float r2 = (v[j].z - mu) * rstd * wv.z + bv.z;
    const float r3 = (v[j].w - mu) * rstd * wv.w + bv.w;
    u32x2 o;
    o[0] = (u32)f2bf(r0) | ((u32)f2bf(r1) << 16);
    o[1] = (u32)f2bf(r2) | ((u32)f2bf(r3) << 16);
    orow[lane + 64 * j] = o;
  }
}

// ---------------------------------------------------------------------------
// Prelude: weight prep (fp32->bf16, padded cat mats/biases) + 3 LayerNorms,
// one flattened dispatch. Blocks [0, NPREP) do prep; rest do LN rows.
// ---------------------------------------------------------------------------
#define NPREP 9985
__global__ __launch_bounds__(256)
void prelude(const float* __restrict__ vp, const float* __restrict__ op,
             const float* __restrict__ vp2, const float* __restrict__ op2,
             const float* __restrict__ so, const float* __restrict__ aw,
             const float* __restrict__ so2, const float* __restrict__ aw2,
             const float* __restrict__ so_b, const float* __restrict__ aw_b,
             const float* __restrict__ so2_b, const float* __restrict__ aw2_b,
             u16* __restrict__ w4, u16* __restrict__ cat1, u16* __restrict__ cat2,
             float* __restrict__ b1, float* __restrict__ b2,
             const float* __restrict__ x0, const float* __restrict__ w0, const float* __restrict__ bb0, u16* __restrict__ o0,
             const float* __restrict__ x1, const float* __restrict__ w1, const float* __restrict__ bb1, u16* __restrict__ o1,
             const float* __restrict__ x2, const float* __restrict__ w2, const float* __restrict__ bb2, u16* __restrict__ o2) {
  const int blk = blockIdx.x;
  if (blk < NPREP) {
    const int i = blk * 256 + threadIdx.x;
    const int NW = 589824;
    if (i < 4 * NW) {
      const int m = i / NW, r = i - m * NW;
      const float* s = (m == 0) ? vp : (m == 1) ? op : (m == 2) ? vp2 : op2;
      w4[i] = f2bf(s[r]);
    } else if (i < 4 * NW + 2 * 98304) {
      const int j = i - 4 * NW;
      const int which = j / 98304;
      const int r = j - which * 98304;
      const int row = r / 768, colr = r - row * 768;
      float v = 0.f;
      if (row < 48) v = (which ? so2 : so)[row * 768 + colr];
      else if (row < 72) v = (which ? aw2 : aw)[(row - 48) * 768 + colr];
      (which ? cat2 : cat1)[r] = f2bf(v);
    } else if (i < 4 * NW + 2 * 98304 + 256) {
      const int j = i - 4 * NW - 2 * 98304;
      const int which = j >> 7, row = j & 127;
      float v = 0.f;
      if (row < 48) v = (which ? so2_b : so_b)[row];
      else if (row < 72) v = (which ? aw2_b : aw_b)[row - 48];
      (which ? b2 : b1)[row] = v;
    }
  } else {
    const int r = blk - NPREP;
    const int sel = r / (LQ / 4);
    const int row = (r - sel * (LQ / 4)) * 4 + (threadIdx.x >> 6);
    const float* x = (sel == 0) ? x0 : (sel == 1) ? x1 : x2;
    const float* w = (sel == 0) ? w0 : (sel == 1) ? w1 : w2;
    const float* b = (sel == 0) ? bb0 : (sel == 1) ? bb1 : bb2;
    u16* o = (sel == 0) ? o0 : (sel == 1) ? o1 : o2;
    ln_wave_body(x, w, b, o, row);
  }
}

// ---------------------------------------------------------------------------
// Wave-per-row LayerNorm, bf16 input -> bf16 output (for qbuf).
// ---------------------------------------------------------------------------
__global__ __launch_bounds__(256)
void ln_bf16_to_bf16(const u16* __restrict__ x, const float* __restrict__ w,
                     const float* __restrict__ b, u16* __restrict__ out) {
  const int row = blockIdx.x * 4 + (threadIdx.x >> 6);
  const int lane = threadIdx.x & 63;
  const u32x2* xr = (const u32x2*)(x + (size_t)row * CC);
  float v[3][4];
  #pragma unroll
  for (int j = 0; j < 3; ++j) {
    const u32x2 u = xr[lane + 64 * j];
    v[j][0] = u2f(u[0] << 16);
    v[j][1] = u2f(u[0] & 0xffff0000u);
    v[j][2] = u2f(u[1] << 16);
    v[j][3] = u2f(u[1] & 0xffff0000u);
  }
  float s = 0.f, ss = 0.f;
  #pragma unroll
  for (int j = 0; j < 3; ++j)
    #pragma unroll
    for (int k = 0; k < 4; ++k) { s += v[j][k]; ss += v[j][k] * v[j][k]; }
  #pragma unroll
  for (int o = 32; o > 0; o >>= 1) {
    s += __shfl_xor(s, o, 64);
    ss += __shfl_xor(ss, o, 64);
  }
  const float mu = s * (1.f / 768.f);
  const float var = ss * (1.f / 768.f) - mu * mu;
  const float rstd = rsqrtf(var + 1e-6f);
  const float4* wr = (const float4*)w;
  const float4* br = (const float4*)b;
  u32x2* orow = (u32x2*)(out + (size_t)row * CC);
  #pragma unroll
  for (int j = 0; j < 3; ++j) {
    const float4 wv = wr[lane + 64 * j];
    const float4 bv = br[lane + 64 * j];
    u32x2 o;
    const float r0 = (v[j][0] - mu) * rstd * wv.x + bv.x;
    const float r1 = (v[j][1] - mu) * rstd * wv.y + bv.y;
    const float r2 = (v[j][2] - mu) * rstd * wv.z + bv.z;
    const float r3 = (v[j][3] - mu) * rstd * wv.w + bv.w;
    o[0] = (u32)f2bf(r0) | ((u32)f2bf(r1) << 16);
    o[1] = (u32)f2bf(r2) | ((u32)f2bf(r3) << 16);
    orow[lane + 64 * j] = o;
  }
}

// ---------------------------------------------------------------------------
// bf16 MFMA GEMM core: TM x 64 tile, BK=64 as two 32-col panels. LDS passed in.
// MODE 0: bf16 out
// MODE 1: f32 out
// MODE 2: bf16 out = f2bf(res_f32[o] + gamma[n]*(acc+bias))   (round-1 op)
// MODE 3: f32 out  = bf2f(res_bf16[o]) + gamma[n]*(acc+bias)  (round-2 op)
// ---------------------------------------------------------------------------
template <int TM, int MODE>
__device__ __forceinline__ void gemm_core(u16* __restrict__ As, u16* __restrict__ Bs,
                                          const u16* __restrict__ A, const u16* __restrict__ W,
                                          const float* __restrict__ bias, void* __restrict__ outv,
                                          const void* __restrict__ res, const float* __restrict__ gamma,
                                          int N, int K, int m0, int n0) {
  constexpr int FI = TM / 32;
  constexpr int NIA = TM / 32;
  const int tid = threadIdx.x;
  const int wv = tid >> 6, lane = tid & 63;
  const int quad = lane >> 4, l16 = lane & 15;
  const int wm = wv & 1, wn = wv >> 1;
  const int sr4 = lane >> 2;
  const int sc = (lane & 3) << 3;

  f32x4 acc[FI][2];
  #pragma unroll
  for (int i = 0; i < FI; ++i)
    #pragma unroll
    for (int j = 0; j < 2; ++j)
      acc[i][j] = (f32x4){0.f, 0.f, 0.f, 0.f};

  for (int k0 = 0; k0 < K; k0 += 64) {
    __syncthreads();
    #pragma unroll
    for (int j = 0; j < NIA; ++j) {
      const int g = wv * NIA + j;
      const int p = g & 1, rb = g >> 1;
      gl_lds16(A + (size_t)(m0 + rb * 16 + sr4) * K + (k0 + p * 32 + sc),
               (char*)As + p * (TM * 64) + rb * 1024 + lane * 16);
    }
    #pragma unroll
    for (int j = 0; j < 2; ++j) {
      const int g = wv * 2 + j;
      const int p = g & 1, rb = g >> 1;
      gl_lds16(W + (size_t)(n0 + rb * 16 + sr4) * K + (k0 + p * 32 + sc),
               (char*)Bs + p * 4096 + rb * 1024 + lane * 16);
    }
    __syncthreads();
    #pragma unroll
    for (int kk = 0; kk < 2; ++kk) {
      bf16x8 af[FI], bfr[2];
      #pragma unroll
      for (int i = 0; i < FI; ++i)
        af[i] = *(const bf16x8*)(As + kk * (TM * 32) + (wm * (TM / 2) + i * 16 + l16) * 32 + quad * 8);
      #pragma unroll
      for (int j = 0; j < 2; ++j)
        bfr[j] = *(const bf16x8*)(Bs + kk * 2048 + (wn * 32 + j * 16 + l16) * 32 + quad * 8);
      #pragma unroll
      for (int i = 0; i < FI; ++i)
        #pragma unroll
        for (int j = 0; j < 2; ++j)
          acc[i][j] = __builtin_amdgcn_mfma_f32_16x16x32_bf16(af[i], bfr[j], acc[i][j], 0, 0, 0);
    }
  }

  #pragma unroll
  for (int i = 0; i < FI; ++i) {
    #pragma unroll
    for (int j = 0; j < 2; ++j) {
      const int col = n0 + wn * 32 + j * 16 + l16;
      const float bs = bias[col];
      #pragma unroll
      for (int r = 0; r < 4; ++r) {
        const int row = m0 + wm * (TM / 2) + i * 16 + quad * 4 + r;
        const float v = acc[i][j][r] + bs;
        const size_t o = (size_t)row * N + col;
        if (MODE == 0) ((u16*)outv)[o] = f2bf(v);
        else if (MODE == 1) ((float*)outv)[o] = v;
        else if (MODE == 2) ((u16*)outv)[o] = f2bf(((const float*)res)[o] + gamma[col] * v);
        else ((float*)outv)[o] = bf2f(((const u16*)res)[o]) + gamma[col] * v;
      }
    }
  }
}

// Fused dispatch: both value-projection GEMMs (1728 blocks) + round-1 small
// offset/aw GEMM (288 blocks) in one 2016-block launch.
__global__ __launch_bounds__(256, 5)
void gemm_fused1(const u16* __restrict__ fn, const u16* __restrict__ wv1, const float* __restrict__ vb1, u16* __restrict__ val1,
                 const u16* __restrict__ fn2, const u16* __restrict__ wv2, const float* __restrict__ vb2, u16* __restrict__ val2,
                 const u16* __restrict__ qn, const u16* __restrict__ cat1, const float* __restrict__ b1, float* __restrict__ offaw) {
  __shared__ u16 As[128 * 64];
  __shared__ u16 Bs[64 * 64];
  const int id = blockIdx.x;
  if (id < 1728) {
    const int z = id / 864, rem = id - z * 864;
    const int x = rem % 72, y = rem / 72;
    gemm_core<128, 0>(As, Bs, z ? fn2 : fn, z ? wv2 : wv1, z ? vb2 : vb1,
                      (void*)(z ? val2 : val1), nullptr, nullptr, CC, CC, x * 128, y * 64);
  } else {
    const int sid = id - 1728;
    const int x = sid % 144, y = sid / 144;
    gemm_core<64, 1>(As, Bs, qn, cat1, b1, (void*)offaw, nullptr, nullptr, 128, CC, x * 64, y * 64);
  }
}

template <int MODE>
__global__ __launch_bounds__(256, 5)
void gemm_bt(const u16* __restrict__ A, const u16* __restrict__ W,
             const float* __restrict__ bias, void* __restrict__ outv,
             const void* __restrict__ res, const float* __restrict__ gamma,
             int N, int K) {
  __shared__ u16 As[128 * 64];
  __shared__ u16 Bs[64 * 64];
  gemm_core<128, MODE>(As, Bs, A, W, bias, outv, res, gamma, N, K, blockIdx.x * 128, blockIdx.y * 64);
}

__global__ __launch_bounds__(256, 5)
void gemm_small(const u16* __restrict__ A, const u16* __restrict__ W,
                const float* __restrict__ bias, float* __restrict__ out,
                int N, int K) {
  __shared__ u16 As[64 * 64];
  __shared__ u16 Bs[64 * 64];
  gemm_core<64, 1>(As, Bs, A, W, bias, (void*)out, nullptr, nullptr, N, K, blockIdx.x * 64, blockIdx.y * 64);
}

// ---------------------------------------------------------------------------
// Deformable sampling: 16 lanes per (q,h), each lane 8 channels (dwordx4).
// Vectorized offset/logit/ref loads; predicated OOB (clamp idx, zero weight).
// ---------------------------------------------------------------------------
__global__ __launch_bounds__(256)
void msds_sample(const u16* __restrict__ value, const float* __restrict__ offaw,
                 const float* __restrict__ ref, u16* __restrict__ out) {
  const int t = blockIdx.x * 256 + threadIdx.x;
  const int pi = t >> 4;
  const int gl = t & 15;
  const int q = pi / NH;
  const int h = pi - q * NH;
  const float4* oaf = (const float4*)(offaw + (size_t)q * 128);
  const float4 of0 = oaf[h * 2];
  const float4 of1 = oaf[h * 2 + 1];
  const float4 lg = oaf[12 + h];
  const float2 rp = ((const float2*)ref)[q];
  const float rx = rp.x * (float)WW - 0.5f;
  const float ry = rp.y * (float)HH - 0.5f;

  const float mx = fmaxf(fmaxf(lg.x, lg.y), fmaxf(lg.z, lg.w));
  const float e0 = __expf(lg.x - mx), e1 = __expf(lg.y - mx);
  const float e2 = __expf(lg.z - mx), e3 = __expf(lg.w - mx);
  const float inv = 1.f / (e0 + e1 + e2 + e3);
  const float wp[4] = {e0 * inv, e1 * inv, e2 * inv, e3 * inv};
  const float ox[4] = {of0.x, of0.z, of1.x, of1.z};
  const float oy[4] = {of0.y, of0.w, of1.y, of1.w};

  float acc[8];
  #pragma unroll
  for (int k = 0; k < 8; ++k) acc[k] = 0.f;

  const u16* vbase = value + h * DH + gl * 8;
  #pragma unroll
  for (int p = 0; p < 4; ++p) {
    const float px = rx + ox[p];
    const float py = ry + oy[p];
    const float fxf = floorf(px), fyf = floorf(py);
    const int x0 = (int)fxf, y0 = (int)fyf;
    const float fx = px - fxf, fy = py - fyf;
    const float cw[4] = {wp[p] * (1.f - fy) * (1.f - fx), wp[p] * (1.f - fy) * fx,
                         wp[p] * fy * (1.f - fx),         wp[p] * fy * fx};
    #pragma unroll
    for (int c = 0; c < 4; ++c) {
      const int yy = y0 + (c >> 1);
      const int xx = x0 + (c & 1);
      const bool valid = (yy >= 0) & (yy < HH) & (xx >= 0) & (xx < WW);
      const int yc = min(max(yy, 0), HH - 1);
      const int xc = min(max(xx, 0), WW - 1);
      const float w2 = valid ? cw[c] : 0.f;
      const u32x4 u = *(const u32x4*)(vbase + (size_t)(yc * WW + xc) * CC);
      #pragma unroll
      for (int k = 0; k < 4; ++k) {
        acc[2 * k]     += w2 * u2f(u[k] << 16);
        acc[2 * k + 1] += w2 * u2f(u[k] & 0xffff0000u);
      }
    }
  }
  u32x4 o;
  #pragma unroll
  for (int k = 0; k < 4; ++k)
    o[k] = (u32)f2bf(acc[2 * k]) | ((u32)f2bf(acc[2 * k + 1]) << 16);
  *(u32x4*)(out + (size_t)q * CC + h * DH + gl * 8) = o;
}

// ---------------------------------------------------------------------------
extern "C" void kernel_launch(void* const* d_in, const int* in_sizes, int n_in,
                              void* d_out, int out_size, void* d_ws, size_t ws_size,
                              hipStream_t stream) {
  const float* query = (const float*)d_in[0];
  const float* refp  = (const float*)d_in[1];
  const float* feat  = (const float*)d_in[2];
  const float* feat2 = (const float*)d_in[3];
  const float* qn_w = (const float*)d_in[6];
  const float* qn_b = (const float*)d_in[7];
  const float* fn_w = (const float*)d_in[8];
  const float* fn_b = (const float*)d_in[9];
  const float* so_w = (const float*)d_in[10];
  const float* so_b = (const float*)d_in[11];
  const float* aw_w = (const float*)d_in[12];
  const float* aw_b = (const float*)d_in[13];
  const float* vp_w = (const float*)d_in[14];
  const float* vp_b = (const float*)d_in[15];
  const float* op_w = (const float*)d_in[16];
  const float* op_b = (const float*)d_in[17];
  const float* gamma = (const float*)d_in[18];
  const float* qn2_w = (const float*)d_in[19];
  const float* qn2_b = (const float*)d_in[20];
  const float* fn2_w = (const float*)d_in[21];
  const float* fn2_b = (const float*)d_in[22];
  const float* so2_w = (const float*)d_in[23];
  const float* so2_b = (const float*)d_in[24];
  const float* aw2_w = (const float*)d_in[25];
  const float* aw2_b = (const float*)d_in[26];
  const float* vp2_w = (const float*)d_in[27];
  const float* vp2_b = (const float*)d_in[28];
  const float* op2_w = (const float*)d_in[29];
  const float* op2_b = (const float*)d_in[30];
  const float* gamma2 = (const float*)d_in[31];

  char* ws = (char*)d_ws;
  size_t off = 0;
  auto alloc = [&](size_t bytes) -> void* {
    void* p = ws + off;
    off += (bytes + 255) & ~(size_t)255;
    return p;
  };
  u16* w4    = (u16*)alloc((size_t)4 * 589824 * 2);
  u16* cat1  = (u16*)alloc((size_t)98304 * 2);
  u16* cat2  = (u16*)alloc((size_t)98304 * 2);
  float* b1  = (float*)alloc(128 * 4);
  float* b2  = (float*)alloc(128 * 4);
  u16* qn    = (u16*)alloc((size_t)LQ * CC * 2);  // reused as qn2
  u16* fn    = (u16*)alloc((size_t)LQ * CC * 2);  // reused as a_pre
  u16* fn2   = (u16*)alloc((size_t)LQ * CC * 2);  // reused as a2_pre
  u16* val1  = (u16*)alloc((size_t)LQ * CC * 2);
  u16* val2  = (u16*)alloc((size_t)LQ * CC * 2);
  float* offaw = (float*)alloc((size_t)LQ * 128 * 4);  // both rounds
  u16* qbuf  = (u16*)alloc((size_t)LQ * CC * 2);       // bf16 residual q

  dim3 blk(256);
  dim3 gbig(LQ / 128, CC / 64), gsm(LQ / 64, 2);

  prelude<<<NPREP + 3 * (LQ / 4), blk, 0, stream>>>(
      vp_w, op_w, vp2_w, op2_w, so_w, aw_w, so2_w, aw2_w,
      so_b, aw_b, so2_b, aw2_b, w4, cat1, cat2, b1, b2,
      query, qn_w, qn_b, qn,
      feat, fn_w, fn_b, fn,
      feat2, fn2_w, fn2_b, fn2);
  gemm_fused1<<<2016, blk, 0, stream>>>(fn, w4, vp_b, val1,
                                        fn2, w4 + 2 * 589824, vp2_b, val2,
                                        qn, cat1, b1, offaw);
  msds_sample<<<LQ * NH / 16, blk, 0, stream>>>(val1, offaw, refp, fn);  // a_pre -> fn
  gemm_bt<2><<<gbig, blk, 0, stream>>>(fn, w4 + 589824, op_b, (void*)qbuf, query, gamma, CC, CC);
  ln_bf16_to_bf16<<<LQ / 4, blk, 0, stream>>>(qbuf, qn2_w, qn2_b, qn);  // qn2 -> qn
  gemm_small<<<gsm, blk, 0, stream>>>(qn, cat2, b2, offaw, 128, CC);
  msds_sample<<<LQ * NH / 16, blk, 0, stream>>>(val2, offaw, refp, fn2);  // a2_pre -> fn2
  gemm_bt<3><<<gbig, blk, 0, stream>>>(fn2, w4 + 3 * 589824, op2_b, d_out, qbuf, gamma2, CC, CC);
}